// Round 8
// baseline (210.995 us; speedup 1.0000x reference)
//
#include <hip/hip_runtime.h>
#include <hip/hip_cooperative_groups.h>

namespace cg = cooperative_groups;

// Problem constants (fixed by setup_inputs): B=8, N=128, C=64, S=64, basis=20
constexpr int N = 128, S = 64;
constexpr float INV_AVG = 1.0f / 49.0f;   // AVG_NOBJ
constexpr float SLOPE = 0.01f;            // leaky_relu neg slope

// Workspace layout (float offsets) — 2.3 MB used
constexpr int WS_BASE = 0;        // [8][128][64]  Cc + E + bias  (j-invariant)
constexpr int WS_DIAG = 65536;    // [8][128][64]  A + D          (diagonal)
constexpr int WS_R    = 131072;   // [8][128][64]  x·W2           (row term)

// ---------------------------------------------------------------------------
// Single cooperative kernel, grid = 1024 x 256 (4 blocks/CU co-resident).
//   Phase A (blocks 0..255): prep — block (n, 4 i-rows) computes
//     base = Cc+E+bias, diag = A+D, R, via one streamed coefs pass (L2-hot)
//     + redundant per-block aggregations. LDS only 15.4 KB (x read from L2).
//   grid.sync()  — device-scope fence, ws visible to all XCDs.
//   Phase B (all 1024 blocks): assemble at 16 waves/CU, 8 float4/thread:
//     out[n,i,j,s] = leaky(base[n,i,s] + R[n,j,s] + d_ij*diag[n,i,s]) * mask
// ---------------------------------------------------------------------------
__global__ __launch_bounds__(256, 4) void fused_coop(
    const float* __restrict__ x,      // [8][128][64]
    const float* __restrict__ mask,   // [8][128][128][1]
    const float* __restrict__ nobj,   // [8]
    const float* __restrict__ coefs,  // [64][64][20]
    const float* __restrict__ bias,   // [64]
    float* __restrict__ ws,
    float* __restrict__ out)          // [8][128][128][64]
{
  __shared__ float ag[256];      // [4][64] {sum/49, sum/nobj, max, min}
  __shared__ float part[3584];   // P1: 3x256 partials; P2: 14x256 partials

  const int tid = threadIdx.x;

  if (blockIdx.x < 256) {
    const int n  = blockIdx.x >> 5;
    const int i0 = (blockIdx.x & 31) << 2;

    // ---- P1: aggregations over i (sum/max/min), x read straight from L2 ----
    {
      const int d = tid & 63, grp = tid >> 6;
      float sm = 0.f, mx = -INFINITY, mn = INFINITY;
#pragma unroll 8
      for (int i = grp * 32; i < grp * 32 + 32; ++i) {
        float v = x[(n * N + i) * 64 + d];   // 256 B/wave, coalesced
        sm += v; mx = fmaxf(mx, v); mn = fminf(mn, v);
      }
      part[grp * 64 + d]       = sm;
      part[256 + grp * 64 + d] = mx;
      part[512 + grp * 64 + d] = mn;
    }
    __syncthreads();
    if (tid < 64) {
      float s0 = part[tid] + part[64 + tid] + part[128 + tid] + part[192 + tid];
      float m0 = fmaxf(fmaxf(part[256 + tid], part[320 + tid]),
                       fmaxf(part[384 + tid], part[448 + tid]));
      float n0 = fminf(fminf(part[512 + tid], part[576 + tid]),
                       fminf(part[640 + tid], part[704 + tid]));
      ag[tid]       = s0 * INV_AVG;   // 'sum'
      ag[64 + tid]  = s0 / nobj[n];   // 'mean'
      ag[128 + tid] = m0;             // 'max'
      ag[192 + tid] = n0;             // 'min'
    }
    __syncthreads();

    // ---- P2: one coefs pass. Thread: s=tid&63, d = k*4+(tid>>6) (wave-uni).
    {
      const int g = tid >> 6;
      const int s = tid & 63;
      float pA[4] = {0,0,0,0}, pR[4] = {0,0,0,0}, pC[4] = {0,0,0,0};
      float pD = 0.f, pE = 0.f;
#pragma unroll
      for (int k = 0; k < 16; ++k) {
        const int e = k * 256 + tid;               // e = d*64 + s
        const int d = e >> 6;                      // wave-uniform
        const float4* cp = (const float4*)(coefs + e * 20);  // 80B rows
        float4 f0 = cp[0], f1 = cp[1], f2 = cp[2], f3 = cp[3], f4v = cp[4];
        float w1v = f0.x + f1.y + f2.z + f3.w;     // b = 0,5,10,15
        float w2v = f0.y + f1.z + f2.w + f4v.x;    // b = 1,6,11,16
        float w3v = f0.z + f1.w + f3.x + f4v.y;    // b = 2,7,12,17
#pragma unroll
        for (int m = 0; m < 4; ++m) {
          float xv = x[(n * N + i0 + m) * 64 + d]; // wave-uniform L2 hit
          pA[m] += xv * w1v;
          pR[m] += xv * w2v;
          pC[m] += xv * w3v;
        }
        // D: cols 3,8,13,18 ; E: cols 4,9,14,19
        pD += ag[d] * f0.w + ag[64 + d] * f2.x + ag[128 + d] * f3.y + ag[192 + d] * f4v.z;
        pE += ag[d] * f1.x + ag[64 + d] * f2.y + ag[128 + d] * f3.z + ag[192 + d] * f4v.w;
      }
#pragma unroll
      for (int m = 0; m < 4; ++m) {
        part[m * 256 + g * 64 + s]        = pA[m];
        part[(4 + m) * 256 + g * 64 + s]  = pC[m];
        part[(8 + m) * 256 + g * 64 + s]  = pR[m];
      }
      part[3072 + g * 64 + s] = pD;
      part[3328 + g * 64 + s] = pE;
    }
    __syncthreads();

    // ---- P3: reduce + fold + write ws (64 threads, coalesced 256 B) ----
    if (tid < 64) {
      const int s = tid;
      float D = part[3072 + s] + part[3072 + 64 + s]
              + part[3072 + 128 + s] + part[3072 + 192 + s];
      float E = part[3328 + s] + part[3328 + 64 + s]
              + part[3328 + 128 + s] + part[3328 + 192 + s];
      float bv = bias[s];
#pragma unroll
      for (int m = 0; m < 4; ++m) {
        float A = part[m * 256 + s] + part[m * 256 + 64 + s]
                + part[m * 256 + 128 + s] + part[m * 256 + 192 + s];
        float C = part[(4 + m) * 256 + s] + part[(4 + m) * 256 + 64 + s]
                + part[(4 + m) * 256 + 128 + s] + part[(4 + m) * 256 + 192 + s];
        float R = part[(8 + m) * 256 + s] + part[(8 + m) * 256 + 64 + s]
                + part[(8 + m) * 256 + 128 + s] + part[(8 + m) * 256 + 192 + s];
        const int o = (n * N + i0 + m) * 64 + s;
        ws[WS_BASE + o] = C + E + bv;
        ws[WS_DIAG + o] = A + D;
        ws[WS_R    + o] = R;
      }
    }
  }

  // ---- grid-wide barrier: prep results visible device-wide ----
  cg::this_grid().sync();

  // ---- Phase B: assemble. 262144 threads x 8 float4 (grid-stride). ----
  const float4* B4 = (const float4*)(ws + WS_BASE);
  const float4* G4 = (const float4*)(ws + WS_DIAG);
  const float4* R4 = (const float4*)(ws + WS_R);
  const int t0 = blockIdx.x * 256 + tid;

#pragma unroll
  for (int it = 0; it < 8; ++it) {
    const int g  = t0 + it * 262144;     // float4 index into out
    const int l  = g & 15;
    const int p  = g >> 4;               // (n*128+i)*128 + j
    const int j  = p & 127;
    const int bi = p >> 7;               // n*128 + i
    const int i  = bi & 127;
    const int n  = bi >> 7;

    float4 b = B4[bi * 16 + l];
    float4 r = R4[(n * N + j) * 16 + l];
    float mk = mask[p];

    float v0 = b.x + r.x;
    float v1 = b.y + r.y;
    float v2 = b.z + r.z;
    float v3 = b.w + r.w;
    if (i == j) {
      float4 dg = G4[bi * 16 + l];
      v0 += dg.x; v1 += dg.y; v2 += dg.z; v3 += dg.w;
    }
    v0 = (v0 >= 0.f) ? v0 : SLOPE * v0;
    v1 = (v1 >= 0.f) ? v1 : SLOPE * v1;
    v2 = (v2 >= 0.f) ? v2 : SLOPE * v2;
    v3 = (v3 >= 0.f) ? v3 : SLOPE * v3;

    float4 o;
    o.x = v0 * mk; o.y = v1 * mk; o.z = v2 * mk; o.w = v3 * mk;
    ((float4*)out)[g] = o;
  }
}

extern "C" void kernel_launch(void* const* d_in, const int* in_sizes, int n_in,
                              void* d_out, int out_size, void* d_ws, size_t ws_size,
                              hipStream_t stream) {
  const float* x     = (const float*)d_in[0];   // [8][128][64]
  const float* mask  = (const float*)d_in[1];   // [8][128][128][1]
  const float* nobj  = (const float*)d_in[2];   // [8]
  const float* coefs = (const float*)d_in[3];   // [64][64][20]
  const float* bias  = (const float*)d_in[4];   // [64]
  float* out = (float*)d_out;                   // [8][128][128][64]
  float* ws  = (float*)d_ws;                    // 196608 floats (~786 KB)

  void* args[] = { (void*)&x, (void*)&mask, (void*)&nobj, (void*)&coefs,
                   (void*)&bias, (void*)&ws, (void*)&out };
  // 1024 blocks x 256 threads, 4 blocks/CU co-resident (launch_bounds(256,4),
  // 15.4 KB LDS) -> valid cooperative grid on 256 CUs.
  hipLaunchCooperativeKernel((const void*)fused_coop, dim3(1024), dim3(256),
                             args, 0, stream);
}

// Round 9
// 81.149 us; speedup vs baseline: 2.6001x; 2.6001x over previous
//
#include <hip/hip_runtime.h>

// Problem constants (fixed by setup_inputs): B=8, N=128, C=64, S=64, basis=20
constexpr int N = 128, S = 64;
constexpr float INV_AVG = 1.0f / 49.0f;   // AVG_NOBJ
constexpr float SLOPE = 0.01f;            // leaky_relu neg slope

// Native 4-float vector for nontemporal stores.
typedef float f4 __attribute__((ext_vector_type(4)));

// Workspace layout (float offsets) — only 2.3 MB used
constexpr int WS_BASE = 0;        // [8][128][64]  Cc + E + bias  (j-invariant)
constexpr int WS_DIAG = 65536;    // [8][128][64]  A + D          (diagonal)
constexpr int WS_R    = 131072;   // [8][128][64]  x·W2           (row term)

// ---------------------------------------------------------------------------
// Kernel 1 (grid 256): block = (n, 4 i-rows). Small LDS (~12.5 KB) so blocks
// co-reside. One streamed coefs pass (L2-hot) computes A,R,Cc per row +
// redundant agg/D/E; writes pre-folded base/diag/R.
//   out[n,i,j,s] = leaky( base[n,i,s] + R[n,j,s] + d_ij*diag[n,i,s] ) * mask
// NOTE (R8 lesson): do NOT fuse these two kernels with a cooperative
// grid.sync() — on MI355X that barrier cost ~100+ us (8 XCDs, device-scope
// spin), vs ~3 us for a plain kernel boundary.
// ---------------------------------------------------------------------------
__global__ __launch_bounds__(256) void prep_kernel(
    const float* __restrict__ x,      // [8][128][64]
    const float* __restrict__ nobj,   // [8]
    const float* __restrict__ coefs,  // [64][64][20]
    const float* __restrict__ bias,   // [64]
    float* __restrict__ ws)
{
  __shared__ float xs[8192];     // x[n] [i][d]
  __shared__ float ag[256];      // [4][64] {sum/49, sum/nobj, max, min}
  __shared__ float part[3584];   // P1: 3x256 partials; P2: 14x256 partials

  const int tid = threadIdx.x;
  const int n   = blockIdx.x >> 5;
  const int i0  = (blockIdx.x & 31) << 2;

  // ---- P0: stage x[n] (32 KB, coalesced float4) ----
  {
    const float4* xg = (const float4*)(x + n * N * 64);
    float4* xs4 = (float4*)xs;
#pragma unroll
    for (int k = 0; k < 8; ++k) xs4[tid + k * 256] = xg[tid + k * 256];
  }
  __syncthreads();

  // ---- P1: aggregations over i (sum/max/min) ----
  {
    const int d = tid & 63, grp = tid >> 6;
    float sm = 0.f, mx = -INFINITY, mn = INFINITY;
    for (int i = grp * 32; i < grp * 32 + 32; ++i) {
      float v = xs[i * 64 + d];          // 2-way bank (free)
      sm += v; mx = fmaxf(mx, v); mn = fminf(mn, v);
    }
    part[grp * 64 + d]       = sm;
    part[256 + grp * 64 + d] = mx;
    part[512 + grp * 64 + d] = mn;
  }
  __syncthreads();
  if (tid < 64) {
    float s0 = part[tid] + part[64 + tid] + part[128 + tid] + part[192 + tid];
    float m0 = fmaxf(fmaxf(part[256 + tid], part[320 + tid]),
                     fmaxf(part[384 + tid], part[448 + tid]));
    float n0 = fminf(fminf(part[512 + tid], part[576 + tid]),
                     fminf(part[640 + tid], part[704 + tid]));
    ag[tid]       = s0 * INV_AVG;   // 'sum'
    ag[64 + tid]  = s0 / nobj[n];   // 'mean'
    ag[128 + tid] = m0;             // 'max'
    ag[192 + tid] = n0;             // 'min'
  }
  __syncthreads();

  // ---- P2: one coefs pass. Thread covers s=tid&63, d = k*4+(tid>>6).
  {
    const int g = tid >> 6;
    const int s = tid & 63;
    float pA[4] = {0,0,0,0}, pR[4] = {0,0,0,0}, pC[4] = {0,0,0,0};
    float pD = 0.f, pE = 0.f;
#pragma unroll
    for (int k = 0; k < 16; ++k) {
      const int e = k * 256 + tid;               // e = d*64 + s
      const int d = e >> 6;                      // wave-uniform
      const float4* cp = (const float4*)(coefs + e * 20);  // 80B rows
      float4 f0 = cp[0], f1 = cp[1], f2 = cp[2], f3 = cp[3], f4v = cp[4];
      float w1v = f0.x + f1.y + f2.z + f3.w;     // b = 0,5,10,15
      float w2v = f0.y + f1.z + f2.w + f4v.x;    // b = 1,6,11,16
      float w3v = f0.z + f1.w + f3.x + f4v.y;    // b = 2,7,12,17
#pragma unroll
      for (int m = 0; m < 4; ++m) {
        float xv = xs[(i0 + m) * 64 + d];        // wave-uniform broadcast
        pA[m] += xv * w1v;
        pR[m] += xv * w2v;
        pC[m] += xv * w3v;
      }
      // D: cols 3,8,13,18 ; E: cols 4,9,14,19
      pD += ag[d] * f0.w + ag[64 + d] * f2.x + ag[128 + d] * f3.y + ag[192 + d] * f4v.z;
      pE += ag[d] * f1.x + ag[64 + d] * f2.y + ag[128 + d] * f3.z + ag[192 + d] * f4v.w;
    }
#pragma unroll
    for (int m = 0; m < 4; ++m) {
      part[m * 256 + g * 64 + s]        = pA[m];
      part[(4 + m) * 256 + g * 64 + s]  = pC[m];
      part[(8 + m) * 256 + g * 64 + s]  = pR[m];
    }
    part[3072 + g * 64 + s] = pD;
    part[3328 + g * 64 + s] = pE;
  }
  __syncthreads();

  // ---- P3: reduce + fold + write (64 threads, 256 B coalesced stores) ----
  if (tid < 64) {
    const int s = tid;
    float D = part[3072 + s] + part[3072 + 64 + s]
            + part[3072 + 128 + s] + part[3072 + 192 + s];
    float E = part[3328 + s] + part[3328 + 64 + s]
            + part[3328 + 128 + s] + part[3328 + 192 + s];
    float bv = bias[s];
#pragma unroll
    for (int m = 0; m < 4; ++m) {
      float A = part[m * 256 + s] + part[m * 256 + 64 + s]
              + part[m * 256 + 128 + s] + part[m * 256 + 192 + s];
      float C = part[(4 + m) * 256 + s] + part[(4 + m) * 256 + 64 + s]
              + part[(4 + m) * 256 + 128 + s] + part[(4 + m) * 256 + 192 + s];
      float R = part[(8 + m) * 256 + s] + part[(8 + m) * 256 + 64 + s]
              + part[(8 + m) * 256 + 128 + s] + part[(8 + m) * 256 + 192 + s];
      const int o = (n * N + i0 + m) * 64 + s;
      ws[WS_BASE + o] = C + E + bv;
      ws[WS_DIAG + o] = A + D;
      ws[WS_R    + o] = R;
    }
  }
}

// ---------------------------------------------------------------------------
// Kernel 2 (grid 8192, deep occupancy): 1 float4 out per thread.
// 2 L2-hot loads + mask + rare diag; nontemporal coalesced float4 store
// (out is write-once -> skip L2 write-allocate, keep L2 for ws/mask).
// ---------------------------------------------------------------------------
__global__ __launch_bounds__(256) void assemble_kernel(
    const float* __restrict__ ws,
    const float* __restrict__ mask,   // [8][128][128][1]
    float* __restrict__ out)          // [8][128][128][64]
{
  const int g  = blockIdx.x * 256 + threadIdx.x;  // float4 index
  const int l  = g & 15;
  const int p  = g >> 4;         // (n*128+i)*128 + j
  const int j  = p & 127;
  const int bi = p >> 7;         // n*128 + i
  const int i  = bi & 127;
  const int n  = bi >> 7;

  const float4* B4 = (const float4*)(ws + WS_BASE);
  const float4* G4 = (const float4*)(ws + WS_DIAG);
  const float4* R4 = (const float4*)(ws + WS_R);

  float4 b = B4[bi * 16 + l];
  float4 r = R4[(n * N + j) * 16 + l];
  float mk = mask[p];

  float v0 = b.x + r.x;
  float v1 = b.y + r.y;
  float v2 = b.z + r.z;
  float v3 = b.w + r.w;
  if (i == j) {
    float4 dg = G4[bi * 16 + l];
    v0 += dg.x; v1 += dg.y; v2 += dg.z; v3 += dg.w;
  }
  v0 = (v0 >= 0.f) ? v0 : SLOPE * v0;
  v1 = (v1 >= 0.f) ? v1 : SLOPE * v1;
  v2 = (v2 >= 0.f) ? v2 : SLOPE * v2;
  v3 = (v3 >= 0.f) ? v3 : SLOPE * v3;

  f4 o;
  o.x = v0 * mk; o.y = v1 * mk; o.z = v2 * mk; o.w = v3 * mk;
  __builtin_nontemporal_store(o, &((f4*)out)[g]);
}

extern "C" void kernel_launch(void* const* d_in, const int* in_sizes, int n_in,
                              void* d_out, int out_size, void* d_ws, size_t ws_size,
                              hipStream_t stream) {
  const float* x     = (const float*)d_in[0];   // [8][128][64]
  const float* mask  = (const float*)d_in[1];   // [8][128][128][1]
  const float* nobj  = (const float*)d_in[2];   // [8]
  const float* coefs = (const float*)d_in[3];   // [64][64][20]
  const float* bias  = (const float*)d_in[4];   // [64]
  float* out = (float*)d_out;                   // [8][128][128][64]
  float* ws  = (float*)d_ws;                    // 196608 floats (~786 KB)

  prep_kernel<<<256, 256, 0, stream>>>(x, nobj, coefs, bias, ws);
  assemble_kernel<<<8192, 256, 0, stream>>>(ws, mask, out);
}